// Round 1
// baseline (537.392 us; speedup 1.0000x reference)
//
#include <hip/hip_runtime.h>
#include <hip/hip_bf16.h>
#include <stdint.h>

// Problem constants
#define BATCH 4
#define SEQ   4096
#define HID   1024
#define NH    16
#define HD    64
#define CS    16
#define NCH   256          // SEQ/CS
#define MROWS 16384        // BATCH*SEQ

typedef __attribute__((ext_vector_type(8))) __bf16 bf16x8;
typedef __attribute__((ext_vector_type(4))) float  f32x4;

__device__ __forceinline__ unsigned short f2bf(float f) {
    union { float f; unsigned u; } x; x.f = f;
    unsigned r = x.u + 0x7FFFu + ((x.u >> 16) & 1u);   // RNE
    return (unsigned short)(r >> 16);
}
__device__ __forceinline__ float bf2f(unsigned short v) {
    union { unsigned u; float f; } x; x.u = ((unsigned)v) << 16;
    return x.f;
}

__device__ __forceinline__ void async_copy16(void* lds, const void* g) {
    __builtin_amdgcn_global_load_lds(
        (const __attribute__((address_space(1))) unsigned int*)g,
        (__attribute__((address_space(3))) unsigned int*)lds,
        16, 0, 0);
}

// ---------------------------------------------------------------- convert
__global__ __launch_bounds__(256) void convert_bf16_kernel(
    const float* __restrict__ in, unsigned short* __restrict__ out, int n4)
{
    int i = blockIdx.x * 256 + threadIdx.x;
    if (i < n4) {
        float4 v = ((const float4*)in)[i];
        ushort4 o;
        o.x = f2bf(v.x); o.y = f2bf(v.y); o.z = f2bf(v.z); o.w = f2bf(v.w);
        ((ushort4*)out)[i] = o;
    }
}

// ---------------------------------------------------------------- GEMM (C = A @ B^T), bf16 in, fp32 out
// A: [M][K] bf16 row-major, Bm: [N][K] bf16 row-major, C: [M][N] fp32
// 128x128 tile, BK=64, 4 waves (2x2 of 64x64), mfma_f32_16x16x32_bf16
__global__ __launch_bounds__(256, 2) void gemm_bt_kernel(
    const unsigned short* __restrict__ A,
    const unsigned short* __restrict__ Bm,
    float* __restrict__ C, int M, int N, int K)
{
    __shared__ unsigned short As[128 * 64];
    __shared__ unsigned short Bs[128 * 64];
    const int t = threadIdx.x;
    const int lane = t & 63, w = t >> 6;
    const int wm = w >> 1, wn = w & 1;
    const size_t bm = (size_t)blockIdx.x * 128;
    const size_t bn = (size_t)blockIdx.y * 128;

    f32x4 acc[4][4];
#pragma unroll
    for (int x = 0; x < 4; x++)
#pragma unroll
        for (int y = 0; y < 4; y++)
            acc[x][y] = (f32x4){0.f, 0.f, 0.f, 0.f};

    // staging: each wave fills 32 rows (4 issues x 8 rows); lane -> row lane>>3, 16B chunk lane&7
    const int srow = lane >> 3;
    const int scol = (lane & 7) * 8;               // ushort units
    const unsigned short* Ag = A + (bm + w * 32 + srow) * (size_t)K + scol;
    const unsigned short* Bg = Bm + (bn + w * 32 + srow) * (size_t)K + scol;
    unsigned short* Al = As + (w * 32 + srow) * 64 + scol;
    unsigned short* Bl = Bs + (w * 32 + srow) * 64 + scol;

    const int fr = lane & 15, fq = lane >> 4;

    for (int k0 = 0; k0 < K; k0 += 64) {
#pragma unroll
        for (int r = 0; r < 4; r++) {
            async_copy16(Al + r * 8 * 64, Ag + (size_t)r * 8 * K + k0);
            async_copy16(Bl + r * 8 * 64, Bg + (size_t)r * 8 * K + k0);
        }
        __syncthreads();
#pragma unroll
        for (int kk = 0; kk < 64; kk += 32) {
            bf16x8 af[4], bfv[4];
#pragma unroll
            for (int x = 0; x < 4; x++) {
                af[x]  = *(const bf16x8*)(As + (wm * 64 + x * 16 + fr) * 64 + kk + fq * 8);
                bfv[x] = *(const bf16x8*)(Bs + (wn * 64 + x * 16 + fr) * 64 + kk + fq * 8);
            }
#pragma unroll
            for (int x = 0; x < 4; x++)
#pragma unroll
                for (int y = 0; y < 4; y++)
                    acc[x][y] = __builtin_amdgcn_mfma_f32_16x16x32_bf16(af[x], bfv[y], acc[x][y], 0, 0, 0);
        }
        __syncthreads();
    }

    // epilogue: C[row][col], row = m-side (fq*4+reg), col = n-side (fr)
#pragma unroll
    for (int x = 0; x < 4; x++) {
#pragma unroll
        for (int y = 0; y < 4; y++) {
            size_t r0 = bm + wm * 64 + x * 16 + fq * 4;
            size_t c  = bn + wn * 64 + y * 16 + fr;
#pragma unroll
            for (int rg = 0; rg < 4; rg++)
                C[(r0 + rg) * (size_t)N + c] = acc[x][y][rg];
        }
    }
}

// ---------------------------------------------------------------- LN + gates + a/b
// One block handles 16 rows. xp fp32 in, writes a (fp32 [m][16]) and b (bf16 [m][1024]).
__global__ __launch_bounds__(256) void ln_gate_kernel(
    const float* __restrict__ xp,
    const float* __restrict__ ln_g, const float* __restrict__ ln_b,
    const float* __restrict__ Wg,   const float* __restrict__ bg,
    const float* __restrict__ eig_raw,
    float* __restrict__ a_out, unsigned short* __restrict__ b_out)
{
    __shared__ unsigned short xr[16][1032];   // normalized rows, bf16, +8 pad
    __shared__ float gl[16][32];              // sigmoid(gates)
    const int t = threadIdx.x;
    const int r = t >> 4, u = t & 15;
    const size_t m0 = (size_t)blockIdx.x * 16;

    // load row r, elements u*4 + i*64, keep fp32 in regs; accumulate stats
    const float* row = xp + (m0 + r) * 1024;
    float4 v[16];
    float s = 0.f, s2 = 0.f;
#pragma unroll
    for (int i = 0; i < 16; i++) {
        v[i] = *(const float4*)(row + u * 4 + i * 64);
        s  += v[i].x + v[i].y + v[i].z + v[i].w;
        s2 += v[i].x * v[i].x + v[i].y * v[i].y + v[i].z * v[i].z + v[i].w * v[i].w;
    }
#pragma unroll
    for (int off = 1; off < 16; off <<= 1) {
        s  += __shfl_xor(s, off, 64);
        s2 += __shfl_xor(s2, off, 64);
    }
    const float mu = s * (1.f / 1024.f);
    const float var = s2 * (1.f / 1024.f) - mu * mu;
    const float sc = rsqrtf(var + 1e-5f);
#pragma unroll
    for (int i = 0; i < 16; i++) {
        const int k = u * 4 + i * 64;
        float4 g4 = *(const float4*)(ln_g + k);
        float4 b4 = *(const float4*)(ln_b + k);
        ushort4 o;
        o.x = f2bf((v[i].x - mu) * sc * g4.x + b4.x);
        o.y = f2bf((v[i].y - mu) * sc * g4.y + b4.y);
        o.z = f2bf((v[i].z - mu) * sc * g4.z + b4.z);
        o.w = f2bf((v[i].w - mu) * sc * g4.w + b4.w);
        *(ushort4*)&xr[r][k] = o;
    }
    __syncthreads();

    // gates: thread (r2 = t>>4, jg = t&15) computes gates 2jg, 2jg+1 of row r2 (full 1024-dot)
    {
        const int r2 = t >> 4, jg = t & 15;
        const float* w0 = Wg + (size_t)(2 * jg) * 1024;
        const float* w1 = w0 + 1024;
        float a0 = 0.f, a1 = 0.f;
        for (int k8 = 0; k8 < 1024; k8 += 8) {
            ushort4 xa = *(const ushort4*)&xr[r2][k8];
            ushort4 xb = *(const ushort4*)&xr[r2][k8 + 4];
            float xf0 = bf2f(xa.x), xf1 = bf2f(xa.y), xf2 = bf2f(xa.z), xf3 = bf2f(xa.w);
            float xf4 = bf2f(xb.x), xf5 = bf2f(xb.y), xf6 = bf2f(xb.z), xf7 = bf2f(xb.w);
            float4 wa0 = *(const float4*)(w0 + k8);
            float4 wb0 = *(const float4*)(w0 + k8 + 4);
            float4 wa1 = *(const float4*)(w1 + k8);
            float4 wb1 = *(const float4*)(w1 + k8 + 4);
            a0 += xf0 * wa0.x + xf1 * wa0.y + xf2 * wa0.z + xf3 * wa0.w
                + xf4 * wb0.x + xf5 * wb0.y + xf6 * wb0.z + xf7 * wb0.w;
            a1 += xf0 * wa1.x + xf1 * wa1.y + xf2 * wa1.z + xf3 * wa1.w
                + xf4 * wb1.x + xf5 * wb1.y + xf6 * wb1.z + xf7 * wb1.w;
        }
        const float g0 = a0 + bg[2 * jg];
        const float g1 = a1 + bg[2 * jg + 1];
        gl[r2][2 * jg]     = 1.f / (1.f + expf(-g0));
        gl[r2][2 * jg + 1] = 1.f / (1.f + expf(-g1));
    }
    __syncthreads();

    // a_out: (row, head) per thread
    {
        const int rr = t >> 4, h = t & 15;
        a_out[(m0 + rr) * 16 + h] = tanhf(eig_raw[h]) * gl[rr][h];
    }
    // b_out: beta[h] * xln, bf16
#pragma unroll
    for (int i = 0; i < 16; i++) {
        const int col = t * 4;
        const float beta = gl[i][16 + (t >> 4)];
        ushort4 xv = *(const ushort4*)&xr[i][col];
        ushort4 o;
        o.x = f2bf(beta * bf2f(xv.x));
        o.y = f2bf(beta * bf2f(xv.y));
        o.z = f2bf(beta * bf2f(xv.z));
        o.w = f2bf(beta * bf2f(xv.w));
        *(ushort4*)(b_out + (m0 + i) * 1024 + col) = o;
    }
}

// ---------------------------------------------------------------- scan phase 1
// Per chunk (b,n): cumprods + hc15 (last-row contribution)
__global__ __launch_bounds__(256) void scan1_kernel(
    const float* __restrict__ a_in,            // [MROWS][16]
    const unsigned short* __restrict__ bmat,   // [MROWS][1024] bf16
    float* __restrict__ cum_out,               // [1024][16][16] (bn, i, h)
    float* __restrict__ hc15)                  // [1024][1024]  (bn, h*64+d)
{
    __shared__ float sa[16][16];
    __shared__ float scum[16][16];
    __shared__ float sm15[16][16];             // [j][h]
    __shared__ unsigned short sb[16][1024];
    const int t = threadIdx.x;
    const int bn = blockIdx.x;
    const size_t m0 = (size_t)(bn >> 8) * SEQ + (size_t)(bn & 255) * 16;

    sa[t >> 4][t & 15] = a_in[(m0 + (t >> 4)) * 16 + (t & 15)];
#pragma unroll
    for (int i = 0; i < 16; i++)
        *(ushort4*)&sb[i][t * 4] = *(const ushort4*)(bmat + (m0 + i) * 1024 + t * 4);
    __syncthreads();

    if (t < 16) {
        float c = 1.f;
#pragma unroll
        for (int i = 0; i < 16; i++) { c *= sa[i][t]; scum[i][t] = c; }
    }
    __syncthreads();

    {
        const int j = t >> 4, h = t & 15;
        const float cum15 = scum[15][h];
        const float cpad = (j == 0) ? 1.f : scum[j - 1][h];
        float mv;
        if (j == 15) mv = 1.f;
        else mv = (fabsf(cpad) > 1e-8f) ? (cum15 / cpad) : 0.f;
        sm15[j][h] = mv;
        cum_out[(size_t)bn * 256 + t] = scum[t >> 4][t & 15];
    }
    __syncthreads();

    {
        const int h = t >> 4, d0 = (t & 15) * 4;
        float a0 = 0.f, a1 = 0.f, a2 = 0.f, a3 = 0.f;
#pragma unroll
        for (int j = 0; j < 16; j++) {
            const float m = sm15[j][h];
            ushort4 bv = *(const ushort4*)&sb[j][h * 64 + d0];
            a0 += m * bf2f(bv.x); a1 += m * bf2f(bv.y);
            a2 += m * bf2f(bv.z); a3 += m * bf2f(bv.w);
        }
        float4 o = { a0, a1, a2, a3 };
        *(float4*)(hc15 + (size_t)bn * 1024 + h * 64 + d0) = o;
    }
}

// ---------------------------------------------------------------- scan phase 2 (sequential carry)
__global__ __launch_bounds__(256) void scan2_kernel(
    const float* __restrict__ cum_buf,   // [1024][256]
    const float* __restrict__ hc15,      // [1024][1024]
    float* __restrict__ carry_in,        // [1024][1024]  (carry entering chunk)
    float* __restrict__ h_final)         // [4][1024]
{
    const int p = blockIdx.x * 256 + threadIdx.x;   // 0..4095
    const int b = p >> 10, hd = p & 1023, h = hd >> 6;
    float carry = 0.f;
#pragma unroll 4
    for (int n = 0; n < NCH; n++) {
        const size_t bn = (size_t)b * NCH + n;
        const float c15 = cum_buf[bn * 256 + 240 + h];
        carry_in[bn * 1024 + hd] = carry;
        carry = c15 * carry + hc15[bn * 1024 + hd];
    }
    h_final[(size_t)b * 1024 + hd] = carry;
}

// ---------------------------------------------------------------- scan phase 3 (reconstruct h_all, bf16)
__global__ __launch_bounds__(256) void scan3_kernel(
    const float* __restrict__ cum_buf,
    const unsigned short* __restrict__ bmat,
    const float* __restrict__ carry_in,
    unsigned short* __restrict__ hall)          // [MROWS][1024] bf16
{
    __shared__ float scum[16][16];
    __shared__ float sm[16][16][16];            // [i][j][h]
    __shared__ unsigned short sb[16][1024];
    const int t = threadIdx.x;
    const int bn = blockIdx.x;
    const size_t m0 = (size_t)(bn >> 8) * SEQ + (size_t)(bn & 255) * 16;

    scum[t >> 4][t & 15] = cum_buf[(size_t)bn * 256 + t];
#pragma unroll
    for (int i = 0; i < 16; i++)
        *(ushort4*)&sb[i][t * 4] = *(const ushort4*)(bmat + (m0 + i) * 1024 + t * 4);
    __syncthreads();

    {
        const int i = t >> 4, h = t & 15;
        const float ci = scum[i][h];
#pragma unroll
        for (int j = 0; j < 16; j++) {
            float mv;
            if (j > i) mv = 0.f;
            else if (j == i) mv = 1.f;
            else {
                const float cpad = (j == 0) ? 1.f : scum[j - 1][h];
                mv = (fabsf(cpad) > 1e-8f) ? (ci / cpad) : 0.f;
            }
            sm[i][j][h] = mv;
        }
    }
    __syncthreads();

    {
        const int h = t >> 4, d0 = (t & 15) * 4;
        float4 car = *(const float4*)(carry_in + (size_t)bn * 1024 + h * 64 + d0);
#pragma unroll
        for (int i = 0; i < 16; i++) {
            float a0 = 0.f, a1 = 0.f, a2 = 0.f, a3 = 0.f;
            for (int j = 0; j <= i; j++) {
                const float m = sm[i][j][h];
                ushort4 bv = *(const ushort4*)&sb[j][h * 64 + d0];
                a0 += m * bf2f(bv.x); a1 += m * bf2f(bv.y);
                a2 += m * bf2f(bv.z); a3 += m * bf2f(bv.w);
            }
            const float ci = scum[i][h];
            ushort4 o;
            o.x = f2bf(ci * car.x + a0);
            o.y = f2bf(ci * car.y + a1);
            o.z = f2bf(ci * car.z + a2);
            o.w = f2bf(ci * car.w + a3);
            *(ushort4*)(hall + (m0 + i) * 1024 + h * 64 + d0) = o;
        }
    }
}

// ---------------------------------------------------------------- launch
extern "C" void kernel_launch(void* const* d_in, const int* in_sizes, int n_in,
                              void* d_out, int out_size, void* d_ws, size_t ws_size,
                              hipStream_t stream)
{
    const float* x       = (const float*)d_in[0];
    const float* W_in    = (const float*)d_in[1];
    const float* ln_g    = (const float*)d_in[2];
    const float* ln_b    = (const float*)d_in[3];
    const float* W_gate  = (const float*)d_in[4];
    const float* b_gate  = (const float*)d_in[5];
    const float* eig_raw = (const float*)d_in[6];
    const float* W_out   = (const float*)d_in[7];
    float* out = (float*)d_out;

    char* ws = (char*)d_ws;
    unsigned short* xb    = (unsigned short*)(ws);                  // 32MB (reused as hall)
    unsigned short* Winb  = (unsigned short*)(ws + 33554432);       // 2MB
    unsigned short* Woutb = (unsigned short*)(ws + 35651584);       // 2MB
    unsigned short* bmat  = (unsigned short*)(ws + 37748736);       // 32MB
    float* a_buf    = (float*)(ws + 71303168);                      // 1MB
    float* cum_buf  = (float*)(ws + 72351744);                      // 1MB
    float* hc15     = (float*)(ws + 73400320);                      // 4MB
    float* carry_in = (float*)(ws + 77594624);                      // 4MB

    float* xp = out;                       // d_out head doubles as xp scratch (overwritten by final GEMM)
    float* h_final = out + 16777216;
    unsigned short* hall = xb;

    convert_bf16_kernel<<<16384, 256, 0, stream>>>(x, xb, 4194304);
    convert_bf16_kernel<<<1024, 256, 0, stream>>>(W_in, Winb, 262144);
    convert_bf16_kernel<<<1024, 256, 0, stream>>>(W_out, Woutb, 262144);

    dim3 gg(128, 8);
    gemm_bt_kernel<<<gg, 256, 0, stream>>>(xb, Winb, xp, MROWS, HID, HID);

    ln_gate_kernel<<<1024, 256, 0, stream>>>(xp, ln_g, ln_b, W_gate, b_gate, eig_raw, a_buf, bmat);

    scan1_kernel<<<1024, 256, 0, stream>>>(a_buf, bmat, cum_buf, hc15);
    scan2_kernel<<<16, 256, 0, stream>>>(cum_buf, hc15, carry_in, h_final);
    scan3_kernel<<<1024, 256, 0, stream>>>(cum_buf, bmat, carry_in, hall);

    gemm_bt_kernel<<<gg, 256, 0, stream>>>(hall, Woutb, out, MROWS, HID, HID);
}

// Round 2
// 336.720 us; speedup vs baseline: 1.5960x; 1.5960x over previous
//
#include <hip/hip_runtime.h>
#include <hip/hip_bf16.h>
#include <stdint.h>

// Problem constants
#define BATCH 4
#define SEQ   4096
#define HID   1024
#define NH    16
#define HD    64
#define CS    16
#define NCH   256          // SEQ/CS
#define MROWS 16384        // BATCH*SEQ

typedef __attribute__((ext_vector_type(8))) __bf16 bf16x8;
typedef __attribute__((ext_vector_type(4))) float  f32x4;

__device__ __forceinline__ unsigned short f2bf(float f) {
    union { float f; unsigned u; } x; x.f = f;
    unsigned r = x.u + 0x7FFFu + ((x.u >> 16) & 1u);   // RNE
    return (unsigned short)(r >> 16);
}
__device__ __forceinline__ float bf2f(unsigned short v) {
    union { unsigned u; float f; } x; x.u = ((unsigned)v) << 16;
    return x.f;
}

__device__ __forceinline__ void async_copy16(void* lds, const void* g) {
    __builtin_amdgcn_global_load_lds(
        (const __attribute__((address_space(1))) unsigned int*)g,
        (__attribute__((address_space(3))) unsigned int*)lds,
        16, 0, 0);
}

// ---------------------------------------------------------------- convert
__global__ __launch_bounds__(256) void convert_bf16_kernel(
    const float* __restrict__ in, unsigned short* __restrict__ out, int n4)
{
    int i = blockIdx.x * 256 + threadIdx.x;
    if (i < n4) {
        float4 v = ((const float4*)in)[i];
        ushort4 o;
        o.x = f2bf(v.x); o.y = f2bf(v.y); o.z = f2bf(v.z); o.w = f2bf(v.w);
        ((ushort4*)out)[i] = o;
    }
}

// ---------------------------------------------------------------- GEMM (C = A @ B^T), bf16 in, fp32 out
// 128x128 tile, BK=64, 4 waves (2x2 of 64x64), mfma_f32_16x16x32_bf16
__global__ __launch_bounds__(256, 2) void gemm_bt_kernel(
    const unsigned short* __restrict__ A,
    const unsigned short* __restrict__ Bm,
    float* __restrict__ C, int M, int N, int K)
{
    __shared__ unsigned short As[128 * 64];
    __shared__ unsigned short Bs[128 * 64];
    const int t = threadIdx.x;
    const int lane = t & 63, w = t >> 6;
    const int wm = w >> 1, wn = w & 1;
    const size_t bm = (size_t)blockIdx.x * 128;
    const size_t bn = (size_t)blockIdx.y * 128;

    f32x4 acc[4][4];
#pragma unroll
    for (int x = 0; x < 4; x++)
#pragma unroll
        for (int y = 0; y < 4; y++)
            acc[x][y] = (f32x4){0.f, 0.f, 0.f, 0.f};

    const int srow = lane >> 3;
    const int scol = (lane & 7) * 8;               // ushort units
    const unsigned short* Ag = A + (bm + w * 32 + srow) * (size_t)K + scol;
    const unsigned short* Bg = Bm + (bn + w * 32 + srow) * (size_t)K + scol;
    unsigned short* Al = As + (w * 32 + srow) * 64 + scol;
    unsigned short* Bl = Bs + (w * 32 + srow) * 64 + scol;

    const int fr = lane & 15, fq = lane >> 4;

    for (int k0 = 0; k0 < K; k0 += 64) {
#pragma unroll
        for (int r = 0; r < 4; r++) {
            async_copy16(Al + r * 8 * 64, Ag + (size_t)r * 8 * K + k0);
            async_copy16(Bl + r * 8 * 64, Bg + (size_t)r * 8 * K + k0);
        }
        __syncthreads();
#pragma unroll
        for (int kk = 0; kk < 64; kk += 32) {
            bf16x8 af[4], bfv[4];
#pragma unroll
            for (int x = 0; x < 4; x++) {
                af[x]  = *(const bf16x8*)(As + (wm * 64 + x * 16 + fr) * 64 + kk + fq * 8);
                bfv[x] = *(const bf16x8*)(Bs + (wn * 64 + x * 16 + fr) * 64 + kk + fq * 8);
            }
#pragma unroll
            for (int x = 0; x < 4; x++)
#pragma unroll
                for (int y = 0; y < 4; y++)
                    acc[x][y] = __builtin_amdgcn_mfma_f32_16x16x32_bf16(af[x], bfv[y], acc[x][y], 0, 0, 0);
        }
        __syncthreads();
    }

#pragma unroll
    for (int x = 0; x < 4; x++) {
#pragma unroll
        for (int y = 0; y < 4; y++) {
            size_t r0 = bm + wm * 64 + x * 16 + fq * 4;
            size_t c  = bn + wn * 64 + y * 16 + fr;
#pragma unroll
            for (int rg = 0; rg < 4; rg++)
                C[(r0 + rg) * (size_t)N + c] = acc[x][y][rg];
        }
    }
}

// ---------------------------------------------------------------- LayerNorm: xp fp32 -> xln bf16
__global__ __launch_bounds__(256) void ln_kernel(
    const float* __restrict__ xp,
    const float* __restrict__ ln_g, const float* __restrict__ ln_b,
    unsigned short* __restrict__ xln)
{
    const int t = threadIdx.x;
    const int r = t >> 4, u = t & 15;
    const size_t m0 = (size_t)blockIdx.x * 16;

    const float* row = xp + (m0 + r) * 1024;
    float4 v[16];
    float s = 0.f, s2 = 0.f;
#pragma unroll
    for (int i = 0; i < 16; i++) {
        v[i] = *(const float4*)(row + u * 4 + i * 64);
        s  += v[i].x + v[i].y + v[i].z + v[i].w;
        s2 += v[i].x * v[i].x + v[i].y * v[i].y + v[i].z * v[i].z + v[i].w * v[i].w;
    }
#pragma unroll
    for (int off = 1; off < 16; off <<= 1) {
        s  += __shfl_xor(s, off, 64);
        s2 += __shfl_xor(s2, off, 64);
    }
    const float mu = s * (1.f / 1024.f);
    const float var = s2 * (1.f / 1024.f) - mu * mu;
    const float sc = rsqrtf(var + 1e-5f);
    unsigned short* orow = xln + (m0 + r) * 1024;
#pragma unroll
    for (int i = 0; i < 16; i++) {
        const int k = u * 4 + i * 64;
        float4 g4 = *(const float4*)(ln_g + k);
        float4 b4 = *(const float4*)(ln_b + k);
        ushort4 o;
        o.x = f2bf((v[i].x - mu) * sc * g4.x + b4.x);
        o.y = f2bf((v[i].y - mu) * sc * g4.y + b4.y);
        o.z = f2bf((v[i].z - mu) * sc * g4.z + b4.z);
        o.w = f2bf((v[i].w - mu) * sc * g4.w + b4.w);
        *(ushort4*)(orow + k) = o;
    }
}

// ---------------------------------------------------------------- gate GEMM: g_buf[m][32] = {a (0..15), beta (16..31)}
// 64-row tile, N=32, K=1024; wave w: rows w*16..+15, cols 0..31
__global__ __launch_bounds__(256) void gate_gemm_kernel(
    const unsigned short* __restrict__ A,    // xln bf16 [MROWS][1024]
    const unsigned short* __restrict__ Wg,   // bf16 [32][1024]
    const float* __restrict__ bg,            // [32]
    const float* __restrict__ eig_raw,       // [16]
    float* __restrict__ g_buf)               // [MROWS][32]
{
    __shared__ unsigned short As[64 * 64];
    __shared__ unsigned short Bs[32 * 64];
    const int t = threadIdx.x, lane = t & 63, w = t >> 6;
    const size_t bm = (size_t)blockIdx.x * 64;

    f32x4 acc[2];
    acc[0] = (f32x4){0.f, 0.f, 0.f, 0.f};
    acc[1] = (f32x4){0.f, 0.f, 0.f, 0.f};

    const int srow = lane >> 3, scol = (lane & 7) * 8;
    const unsigned short* Ag = A + (bm + w * 16 + srow) * 1024 + scol;
    unsigned short* Al = As + (w * 16 + srow) * 64 + scol;
    const unsigned short* Bg = Wg + (w * 8 + srow) * 1024 + scol;
    unsigned short* Bl = Bs + (w * 8 + srow) * 64 + scol;

    const int fr = lane & 15, fq = lane >> 4;

    for (int k0 = 0; k0 < 1024; k0 += 64) {
        async_copy16(Al, Ag + k0);
        async_copy16(Al + 8 * 64, Ag + 8 * 1024 + k0);
        async_copy16(Bl, Bg + k0);
        __syncthreads();
#pragma unroll
        for (int kk = 0; kk < 64; kk += 32) {
            bf16x8 af = *(const bf16x8*)(As + (w * 16 + fr) * 64 + kk + fq * 8);
            bf16x8 b0 = *(const bf16x8*)(Bs + (fr) * 64 + kk + fq * 8);
            bf16x8 b1 = *(const bf16x8*)(Bs + (16 + fr) * 64 + kk + fq * 8);
            acc[0] = __builtin_amdgcn_mfma_f32_16x16x32_bf16(af, b0, acc[0], 0, 0, 0);
            acc[1] = __builtin_amdgcn_mfma_f32_16x16x32_bf16(af, b1, acc[1], 0, 0, 0);
        }
        __syncthreads();
    }

#pragma unroll
    for (int y = 0; y < 2; y++) {
        const int col = y * 16 + fr;
        const float bias = bg[col];
        const float ev = (col < 16) ? tanhf(eig_raw[col]) : 1.f;
#pragma unroll
        for (int rg = 0; rg < 4; rg++) {
            const size_t row = bm + w * 16 + fq * 4 + rg;
            const float gv = acc[y][rg] + bias;
            const float sig = 1.f / (1.f + expf(-gv));
            g_buf[row * 32 + col] = ev * sig;   // a for col<16, beta for col>=16
        }
    }
}

// ---------------------------------------------------------------- scan phase 1
// Per chunk (b,n): cumprods + hc15 (last-row contribution). beta folded into M.
__global__ __launch_bounds__(256) void scan1_kernel(
    const float* __restrict__ g_buf,           // [MROWS][32]
    const unsigned short* __restrict__ xln,    // [MROWS][1024] bf16
    float* __restrict__ cum_out,               // [1024][16][16] (bn, i, h)
    float* __restrict__ hc15)                  // [1024][1024]  (bn, h*64+d)
{
    __shared__ float sa[16][16];
    __shared__ float sbeta[16][16];
    __shared__ float scum[16][16];
    __shared__ float sm15[16][16];             // [j][h], includes beta
    __shared__ unsigned short sx[16][1024];
    const int t = threadIdx.x;
    const int bn = blockIdx.x;
    const size_t m0 = (size_t)(bn >> 8) * SEQ + (size_t)(bn & 255) * 16;

    sa[t >> 4][t & 15]    = g_buf[(m0 + (t >> 4)) * 32 + (t & 15)];
    sbeta[t >> 4][t & 15] = g_buf[(m0 + (t >> 4)) * 32 + 16 + (t & 15)];
#pragma unroll
    for (int i = 0; i < 16; i++)
        *(ushort4*)&sx[i][t * 4] = *(const ushort4*)(xln + (m0 + i) * 1024 + t * 4);
    __syncthreads();

    if (t < 16) {
        float c = 1.f;
#pragma unroll
        for (int i = 0; i < 16; i++) { c *= sa[i][t]; scum[i][t] = c; }
    }
    __syncthreads();

    {
        const int j = t >> 4, h = t & 15;
        const float cum15 = scum[15][h];
        const float cpad = (j == 0) ? 1.f : scum[j - 1][h];
        float mv;
        if (j == 15) mv = 1.f;
        else mv = (fabsf(cpad) > 1e-8f) ? (cum15 / cpad) : 0.f;
        sm15[j][h] = mv * sbeta[j][h];
        cum_out[(size_t)bn * 256 + t] = scum[t >> 4][t & 15];
    }
    __syncthreads();

    {
        const int h = t >> 4, d0 = (t & 15) * 4;
        float a0 = 0.f, a1 = 0.f, a2 = 0.f, a3 = 0.f;
#pragma unroll
        for (int j = 0; j < 16; j++) {
            const float m = sm15[j][h];
            ushort4 bv = *(const ushort4*)&sx[j][h * 64 + d0];
            a0 += m * bf2f(bv.x); a1 += m * bf2f(bv.y);
            a2 += m * bf2f(bv.z); a3 += m * bf2f(bv.w);
        }
        float4 o = { a0, a1, a2, a3 };
        *(float4*)(hc15 + (size_t)bn * 1024 + h * 64 + d0) = o;
    }
}

// ---------------------------------------------------------------- scan phase 2 (sequential carry)
__global__ __launch_bounds__(256) void scan2_kernel(
    const float* __restrict__ cum_buf,   // [1024][256]
    const float* __restrict__ hc15,      // [1024][1024]
    float* __restrict__ carry_in,        // [1024][1024]
    float* __restrict__ h_final)         // [4][1024]
{
    const int p = blockIdx.x * 256 + threadIdx.x;   // 0..4095
    const int b = p >> 10, hd = p & 1023, h = hd >> 6;
    float carry = 0.f;
#pragma unroll 4
    for (int n = 0; n < NCH; n++) {
        const size_t bn = (size_t)b * NCH + n;
        const float c15 = cum_buf[bn * 256 + 240 + h];
        carry_in[bn * 1024 + hd] = carry;
        carry = c15 * carry + hc15[bn * 1024 + hd];
    }
    h_final[(size_t)b * 1024 + hd] = carry;
}

// ---------------------------------------------------------------- scan phase 3 (reconstruct h_all, bf16)
__global__ __launch_bounds__(256) void scan3_kernel(
    const float* __restrict__ cum_buf,
    const float* __restrict__ g_buf,
    const unsigned short* __restrict__ xln,
    const float* __restrict__ carry_in,
    unsigned short* __restrict__ hall)          // [MROWS][1024] bf16
{
    __shared__ float scum[16][16];
    __shared__ float sbeta[16][16];
    __shared__ float sm[16][16][16];            // [i][j][h], includes beta
    __shared__ unsigned short sx[16][1024];
    const int t = threadIdx.x;
    const int bn = blockIdx.x;
    const size_t m0 = (size_t)(bn >> 8) * SEQ + (size_t)(bn & 255) * 16;

    scum[t >> 4][t & 15]  = cum_buf[(size_t)bn * 256 + t];
    sbeta[t >> 4][t & 15] = g_buf[(m0 + (t >> 4)) * 32 + 16 + (t & 15)];
#pragma unroll
    for (int i = 0; i < 16; i++)
        *(ushort4*)&sx[i][t * 4] = *(const ushort4*)(xln + (m0 + i) * 1024 + t * 4);
    __syncthreads();

    {
        const int i = t >> 4, h = t & 15;
        const float ci = scum[i][h];
#pragma unroll
        for (int j = 0; j < 16; j++) {
            float mv;
            if (j > i) mv = 0.f;
            else if (j == i) mv = 1.f;
            else {
                const float cpad = (j == 0) ? 1.f : scum[j - 1][h];
                mv = (fabsf(cpad) > 1e-8f) ? (ci / cpad) : 0.f;
            }
            sm[i][j][h] = mv * sbeta[j][h];
        }
    }
    __syncthreads();

    {
        const int h = t >> 4, d0 = (t & 15) * 4;
        float4 car = *(const float4*)(carry_in + (size_t)bn * 1024 + h * 64 + d0);
#pragma unroll
        for (int i = 0; i < 16; i++) {
            float a0 = 0.f, a1 = 0.f, a2 = 0.f, a3 = 0.f;
            for (int j = 0; j <= i; j++) {
                const float m = sm[i][j][h];
                ushort4 bv = *(const ushort4*)&sx[j][h * 64 + d0];
                a0 += m * bf2f(bv.x); a1 += m * bf2f(bv.y);
                a2 += m * bf2f(bv.z); a3 += m * bf2f(bv.w);
            }
            const float ci = scum[i][h];
            ushort4 o;
            o.x = f2bf(ci * car.x + a0);
            o.y = f2bf(ci * car.y + a1);
            o.z = f2bf(ci * car.z + a2);
            o.w = f2bf(ci * car.w + a3);
            *(ushort4*)(hall + (m0 + i) * 1024 + h * 64 + d0) = o;
        }
    }
}

// ---------------------------------------------------------------- launch
extern "C" void kernel_launch(void* const* d_in, const int* in_sizes, int n_in,
                              void* d_out, int out_size, void* d_ws, size_t ws_size,
                              hipStream_t stream)
{
    const float* x       = (const float*)d_in[0];
    const float* W_in    = (const float*)d_in[1];
    const float* ln_g    = (const float*)d_in[2];
    const float* ln_b    = (const float*)d_in[3];
    const float* W_gate  = (const float*)d_in[4];
    const float* b_gate  = (const float*)d_in[5];
    const float* eig_raw = (const float*)d_in[6];
    const float* W_out   = (const float*)d_in[7];
    float* out = (float*)d_out;

    char* ws = (char*)d_ws;
    // region0: xb (x bf16) for gemm1, then overwritten by xln
    unsigned short* xb   = (unsigned short*)(ws);                   // 32MB
    unsigned short* xln  = (unsigned short*)(ws);                   // reuses region0 after gemm1
    unsigned short* hall = (unsigned short*)(ws + 33554432);        // 32MB
    unsigned short* Wb   = (unsigned short*)(ws + 67108864);        // 2MB (W_in then W_out)
    unsigned short* Wgb  = (unsigned short*)(ws + 69206016);        // 64KB
    float* g_buf    = (float*)(ws + 69271552);                      // 2MB [MROWS][32]
    float* cum_buf  = (float*)(ws + 71368704);                      // 1MB
    float* hc15     = (float*)(ws + 72417280);                      // 4MB
    float* carry_in = (float*)(ws + 76611584);                      // 4MB -> end 80,805,888

    float* xp = out;                       // d_out head doubles as xp scratch
    float* h_final = out + 16777216;

    convert_bf16_kernel<<<16384, 256, 0, stream>>>(x, xb, 4194304);
    convert_bf16_kernel<<<1024, 256, 0, stream>>>(W_in, Wb, 262144);
    convert_bf16_kernel<<<32, 256, 0, stream>>>(W_gate, Wgb, 8192);

    dim3 gg(128, 8);
    gemm_bt_kernel<<<gg, 256, 0, stream>>>(xb, Wb, xp, MROWS, HID, HID);

    ln_kernel<<<1024, 256, 0, stream>>>(xp, ln_g, ln_b, xln);   // overwrites xb region

    gate_gemm_kernel<<<256, 256, 0, stream>>>(xln, Wgb, b_gate, eig_raw, g_buf);

    scan1_kernel<<<1024, 256, 0, stream>>>(g_buf, xln, cum_buf, hc15);
    scan2_kernel<<<16, 256, 0, stream>>>(cum_buf, hc15, carry_in, h_final);
    scan3_kernel<<<1024, 256, 0, stream>>>(cum_buf, g_buf, xln, carry_in, hall);

    convert_bf16_kernel<<<1024, 256, 0, stream>>>(W_out, Wb, 262144);   // reuse Wb
    gemm_bt_kernel<<<gg, 256, 0, stream>>>(hall, Wb, out, MROWS, HID, HID);
}

// Round 3
// 314.737 us; speedup vs baseline: 1.7074x; 1.0698x over previous
//
#include <hip/hip_runtime.h>
#include <hip/hip_bf16.h>
#include <stdint.h>

// Problem constants
#define BATCH 4
#define SEQ   4096
#define HID   1024
#define NH    16
#define HD    64
#define CS    16
#define NCH   256          // SEQ/CS
#define MROWS 16384        // BATCH*SEQ

typedef __attribute__((ext_vector_type(8))) __bf16 bf16x8;
typedef __attribute__((ext_vector_type(4))) float  f32x4;

__device__ __forceinline__ unsigned short f2bf(float f) {
    union { float f; unsigned u; } x; x.f = f;
    unsigned r = x.u + 0x7FFFu + ((x.u >> 16) & 1u);   // RNE
    return (unsigned short)(r >> 16);
}
__device__ __forceinline__ float bf2f(unsigned short v) {
    union { unsigned u; float f; } x; x.u = ((unsigned)v) << 16;
    return x.f;
}

__device__ __forceinline__ void async_copy16(void* lds, const void* g) {
    __builtin_amdgcn_global_load_lds(
        (const __attribute__((address_space(1))) unsigned int*)g,
        (__attribute__((address_space(3))) unsigned int*)lds,
        16, 0, 0);
}

// ---------------------------------------------------------------- convert (all inputs, one kernel)
// x -> xb bf16; W_in -> Wib; W_out -> Wob; W_gate -> WgT bf16 TRANSPOSED [1024][32]
__global__ __launch_bounds__(256) void convert_all_kernel(
    const float* __restrict__ x, const float* __restrict__ W_in,
    const float* __restrict__ W_out, const float* __restrict__ W_gate,
    unsigned short* __restrict__ xb, unsigned short* __restrict__ Wib,
    unsigned short* __restrict__ Wob, unsigned short* __restrict__ WgT)
{
    int i = blockIdx.x * 256 + threadIdx.x;
    if (i < 4194304) {
        float4 v = ((const float4*)x)[i];
        ushort4 o;
        o.x = f2bf(v.x); o.y = f2bf(v.y); o.z = f2bf(v.z); o.w = f2bf(v.w);
        ((ushort4*)xb)[i] = o;
    } else if (i < 4456448) {
        int j = i - 4194304;
        float4 v = ((const float4*)W_in)[j];
        ushort4 o;
        o.x = f2bf(v.x); o.y = f2bf(v.y); o.z = f2bf(v.z); o.w = f2bf(v.w);
        ((ushort4*)Wib)[j] = o;
    } else if (i < 4718592) {
        int j = i - 4456448;
        float4 v = ((const float4*)W_out)[j];
        ushort4 o;
        o.x = f2bf(v.x); o.y = f2bf(v.y); o.z = f2bf(v.z); o.w = f2bf(v.w);
        ((ushort4*)Wob)[j] = o;
    } else if (i < 4726784) {
        int j = i - 4718592;              // 0..8191
        int g  = j >> 8;                  // gate row 0..31
        int kq = j & 255;                 // k/4
        float4 v = ((const float4*)W_gate)[g * 256 + kq];
        int k0 = kq * 4;
        WgT[(k0 + 0) * 32 + g] = f2bf(v.x);
        WgT[(k0 + 1) * 32 + g] = f2bf(v.y);
        WgT[(k0 + 2) * 32 + g] = f2bf(v.z);
        WgT[(k0 + 3) * 32 + g] = f2bf(v.w);
    }
}

// ---------------------------------------------------------------- GEMM (C = A @ B^T), bf16 in, fp32 out
// 128x128 tile, BK=64, 4 waves (2x2 of 64x64), mfma_f32_16x16x32_bf16
// LDS bank-conflict fix: XOR swizzle — physical 16B chunk = logical ^ (row&7)
__global__ __launch_bounds__(256, 2) void gemm_bt_kernel(
    const unsigned short* __restrict__ A,
    const unsigned short* __restrict__ Bm,
    float* __restrict__ C, int M, int N, int K)
{
    __shared__ unsigned short As[128 * 64];
    __shared__ unsigned short Bs[128 * 64];
    const int t = threadIdx.x;
    const int lane = t & 63, w = t >> 6;
    const int wm = w >> 1, wn = w & 1;
    const size_t bm = (size_t)blockIdx.x * 128;
    const size_t bn = (size_t)blockIdx.y * 128;

    f32x4 acc[4][4];
#pragma unroll
    for (int x = 0; x < 4; x++)
#pragma unroll
        for (int y = 0; y < 4; y++)
            acc[x][y] = (f32x4){0.f, 0.f, 0.f, 0.f};

    const int srow = lane >> 3;
    const int gc   = (lane & 7) ^ (srow & 7);      // swizzled global chunk
    const int scol = gc * 8;                       // ushort units
    const unsigned short* Ag = A + (bm + w * 32 + srow) * (size_t)K + scol;
    const unsigned short* Bg = Bm + (bn + w * 32 + srow) * (size_t)K + scol;
    // LDS dst stays linear in lane (global_load_lds constraint)
    unsigned short* Al = As + (w * 32 + srow) * 64 + (lane & 7) * 8;
    unsigned short* Bl = Bs + (w * 32 + srow) * 64 + (lane & 7) * 8;

    const int fr = lane & 15, fq = lane >> 4;
    const int rl = fr & 7;                         // row-low bits for read-side swizzle

    for (int k0 = 0; k0 < K; k0 += 64) {
#pragma unroll
        for (int r = 0; r < 4; r++) {
            async_copy16(Al + r * 8 * 64, Ag + (size_t)r * 8 * K + k0);
            async_copy16(Bl + r * 8 * 64, Bg + (size_t)r * 8 * K + k0);
        }
        __syncthreads();
#pragma unroll
        for (int kk = 0; kk < 64; kk += 32) {
            const int c = (kk >> 3) + fq;          // logical chunk 0..7
            const int pc = c ^ rl;                 // physical chunk
            bf16x8 af[4], bfv[4];
#pragma unroll
            for (int x = 0; x < 4; x++) {
                af[x]  = *(const bf16x8*)(As + (wm * 64 + x * 16 + fr) * 64 + pc * 8);
                bfv[x] = *(const bf16x8*)(Bs + (wn * 64 + x * 16 + fr) * 64 + pc * 8);
            }
#pragma unroll
            for (int x = 0; x < 4; x++)
#pragma unroll
                for (int y = 0; y < 4; y++)
                    acc[x][y] = __builtin_amdgcn_mfma_f32_16x16x32_bf16(af[x], bfv[y], acc[x][y], 0, 0, 0);
        }
        __syncthreads();
    }

#pragma unroll
    for (int x = 0; x < 4; x++) {
#pragma unroll
        for (int y = 0; y < 4; y++) {
            size_t r0 = bm + wm * 64 + x * 16 + fq * 4;
            size_t c  = bn + wn * 64 + y * 16 + fr;
#pragma unroll
            for (int rg = 0; rg < 4; rg++)
                C[(r0 + rg) * (size_t)N + c] = acc[x][y][rg];
        }
    }
}

// ---------------------------------------------------------------- mid: LN + gates + scan1, one block per chunk
__global__ __launch_bounds__(256) void mid_kernel(
    const float* __restrict__ xp,
    const float* __restrict__ ln_g, const float* __restrict__ ln_b,
    const unsigned short* __restrict__ WgT,   // bf16 [1024][32]
    const float* __restrict__ bg, const float* __restrict__ eig_raw,
    unsigned short* __restrict__ xln,         // out: [MROWS][1024] bf16
    float* __restrict__ beta_buf,             // out: [MROWS][16]
    float* __restrict__ cum_out,              // out: [1024][16][16]
    float* __restrict__ c15c,                 // out: [1024][16]
    float* __restrict__ hc15)                 // out: [1024][1024]
{
    __shared__ unsigned short sx[16][1032];   // padded: stride 2064B -> 2-way banks
    __shared__ unsigned short swg[1024 * 32]; // [k][n], 64KB
    __shared__ float sg[16][32];
    __shared__ float scum[16][16];
    __shared__ float sm15[16][16];
    const int t = threadIdx.x;
    const int bn = blockIdx.x;
    const size_t m0 = (size_t)(bn >> 8) * SEQ + (size_t)(bn & 255) * 16;

    // stage WgT 64KB async (16 x 4KB, contiguous lane mapping)
#pragma unroll
    for (int i = 0; i < 16; i++)
        async_copy16((char*)swg + (i * 256 + t) * 16, (const char*)WgT + (i * 256 + t) * 16);

    // ---- LayerNorm (row r = t>>4, 64 elems per thread)
    const int r = t >> 4, u = t & 15;
    const float* row = xp + (m0 + r) * 1024;
    float4 v[16];
    float s = 0.f, s2 = 0.f;
#pragma unroll
    for (int i = 0; i < 16; i++) {
        v[i] = *(const float4*)(row + u * 4 + i * 64);
        s  += v[i].x + v[i].y + v[i].z + v[i].w;
        s2 += v[i].x * v[i].x + v[i].y * v[i].y + v[i].z * v[i].z + v[i].w * v[i].w;
    }
#pragma unroll
    for (int off = 1; off < 16; off <<= 1) {
        s  += __shfl_xor(s, off, 64);
        s2 += __shfl_xor(s2, off, 64);
    }
    const float mu = s * (1.f / 1024.f);
    const float var = s2 * (1.f / 1024.f) - mu * mu;
    const float sc = rsqrtf(var + 1e-5f);
    unsigned short* orow = xln + (m0 + r) * 1024;
#pragma unroll
    for (int i = 0; i < 16; i++) {
        const int k = u * 4 + i * 64;
        float4 g4 = *(const float4*)(ln_g + k);
        float4 b4 = *(const float4*)(ln_b + k);
        ushort4 o;
        o.x = f2bf((v[i].x - mu) * sc * g4.x + b4.x);
        o.y = f2bf((v[i].y - mu) * sc * g4.y + b4.y);
        o.z = f2bf((v[i].z - mu) * sc * g4.z + b4.z);
        o.w = f2bf((v[i].w - mu) * sc * g4.w + b4.w);
        *(ushort4*)&sx[r][k] = o;
        *(ushort4*)(orow + k) = o;
    }
    __syncthreads();   // drains global_load_lds too

    // ---- gates: thread (r2, jg) computes gates 2jg, 2jg+1 of row r2 from LDS
    {
        const int r2 = t >> 4, jg = t & 15;
        float a0 = 0.f, a1 = 0.f;
        for (int k8 = 0; k8 < 1024; k8 += 8) {
            ushort4 xa = *(const ushort4*)&sx[r2][k8];
            ushort4 xb2 = *(const ushort4*)&sx[r2][k8 + 4];
            float xf[8] = { bf2f(xa.x), bf2f(xa.y), bf2f(xa.z), bf2f(xa.w),
                            bf2f(xb2.x), bf2f(xb2.y), bf2f(xb2.z), bf2f(xb2.w) };
#pragma unroll
            for (int kk = 0; kk < 8; kk++) {
                unsigned wpair = *(const unsigned*)&swg[(k8 + kk) * 32 + 2 * jg];
                a0 += xf[kk] * bf2f((unsigned short)(wpair & 0xffff));
                a1 += xf[kk] * bf2f((unsigned short)(wpair >> 16));
            }
        }
        const float g0 = a0 + bg[2 * jg];
        const float g1 = a1 + bg[2 * jg + 1];
        sg[r2][2 * jg]     = 1.f / (1.f + expf(-g0));
        sg[r2][2 * jg + 1] = 1.f / (1.f + expf(-g1));
    }
    __syncthreads();

    // ---- cumprod of a = tanh(eig)*alpha (16 chains)
    if (t < 16) {
        const float ev = tanhf(eig_raw[t]);
        float c = 1.f;
#pragma unroll
        for (int i = 0; i < 16; i++) { c *= ev * sg[i][t]; scum[i][t] = c; }
    }
    // beta out
    {
        const int rr = t >> 4, h = t & 15;
        beta_buf[(m0 + rr) * 16 + h] = sg[rr][16 + h];
    }
    __syncthreads();

    // ---- M15 (with beta folded), cum/c15 out
    {
        const int j = t >> 4, h = t & 15;
        const float cum15 = scum[15][h];
        const float cpad = (j == 0) ? 1.f : scum[j - 1][h];
        float mv;
        if (j == 15) mv = 1.f;
        else mv = (fabsf(cpad) > 1e-8f) ? (cum15 / cpad) : 0.f;
        sm15[j][h] = mv * sg[j][16 + h];
        cum_out[(size_t)bn * 256 + t] = scum[j][h];
        if (t < 16) c15c[bn * 16 + t] = scum[15][t];
    }
    __syncthreads();

    // ---- hc15
    {
        const int h = t >> 4, d0 = (t & 15) * 4;
        float a0 = 0.f, a1 = 0.f, a2 = 0.f, a3 = 0.f;
#pragma unroll
        for (int j = 0; j < 16; j++) {
            const float m = sm15[j][h];
            ushort4 bv = *(const ushort4*)&sx[j][h * 64 + d0];
            a0 += m * bf2f(bv.x); a1 += m * bf2f(bv.y);
            a2 += m * bf2f(bv.z); a3 += m * bf2f(bv.w);
        }
        float4 o = { a0, a1, a2, a3 };
        *(float4*)(hc15 + (size_t)bn * 1024 + h * 64 + d0) = o;
    }
}

// ---------------------------------------------------------------- scan phase 2 (sequential carry)
__global__ __launch_bounds__(256) void scan2_kernel(
    const float* __restrict__ c15c,      // [1024][16]
    const float* __restrict__ hc15,      // [1024][1024]
    float* __restrict__ carry_in,        // [1024][1024]
    float* __restrict__ h_final)         // [4][1024]
{
    const int p = blockIdx.x * 256 + threadIdx.x;   // 0..4095
    const int b = p >> 10, hd = p & 1023, h = hd >> 6;
    float carry = 0.f;
#pragma unroll 8
    for (int n = 0; n < NCH; n++) {
        const size_t bn = (size_t)b * NCH + n;
        const float c15 = c15c[bn * 16 + h];
        carry_in[bn * 1024 + hd] = carry;
        carry = c15 * carry + hc15[bn * 1024 + hd];
    }
    h_final[(size_t)b * 1024 + hd] = carry;
}

// ---------------------------------------------------------------- scan phase 3 (reconstruct h_all, bf16)
__global__ __launch_bounds__(256) void scan3_kernel(
    const float* __restrict__ cum_buf,
    const float* __restrict__ beta_buf,
    const unsigned short* __restrict__ xln,
    const float* __restrict__ carry_in,
    unsigned short* __restrict__ hall)          // [MROWS][1024] bf16
{
    __shared__ float scum[16][16];
    __shared__ float sbeta[16][16];
    __shared__ float sm[16][16][16];            // [i][j][h], includes beta
    __shared__ unsigned short sx[16][1024];
    const int t = threadIdx.x;
    const int bn = blockIdx.x;
    const size_t m0 = (size_t)(bn >> 8) * SEQ + (size_t)(bn & 255) * 16;

    scum[t >> 4][t & 15]  = cum_buf[(size_t)bn * 256 + t];
    sbeta[t >> 4][t & 15] = beta_buf[(m0 + (t >> 4)) * 16 + (t & 15)];
#pragma unroll
    for (int i = 0; i < 16; i++)
        *(ushort4*)&sx[i][t * 4] = *(const ushort4*)(xln + (m0 + i) * 1024 + t * 4);
    __syncthreads();

    {
        const int i = t >> 4, h = t & 15;
        const float ci = scum[i][h];
#pragma unroll
        for (int j = 0; j < 16; j++) {
            float mv;
            if (j > i) mv = 0.f;
            else if (j == i) mv = 1.f;
            else {
                const float cpad = (j == 0) ? 1.f : scum[j - 1][h];
                mv = (fabsf(cpad) > 1e-8f) ? (ci / cpad) : 0.f;
            }
            sm[i][j][h] = mv * sbeta[j][h];
        }
    }
    __syncthreads();

    {
        const int h = t >> 4, d0 = (t & 15) * 4;
        float4 car = *(const float4*)(carry_in + (size_t)bn * 1024 + h * 64 + d0);
#pragma unroll
        for (int i = 0; i < 16; i++) {
            float a0 = 0.f, a1 = 0.f, a2 = 0.f, a3 = 0.f;
            for (int j = 0; j <= i; j++) {
                const float m = sm[i][j][h];
                ushort4 bv = *(const ushort4*)&sx[j][h * 64 + d0];
                a0 += m * bf2f(bv.x); a1 += m * bf2f(bv.y);
                a2 += m * bf2f(bv.z); a3 += m * bf2f(bv.w);
            }
            const float ci = scum[i][h];
            ushort4 o;
            o.x = f2bf(ci * car.x + a0);
            o.y = f2bf(ci * car.y + a1);
            o.z = f2bf(ci * car.z + a2);
            o.w = f2bf(ci * car.w + a3);
            *(ushort4*)(hall + (m0 + i) * 1024 + h * 64 + d0) = o;
        }
    }
}

// ---------------------------------------------------------------- launch
extern "C" void kernel_launch(void* const* d_in, const int* in_sizes, int n_in,
                              void* d_out, int out_size, void* d_ws, size_t ws_size,
                              hipStream_t stream)
{
    const float* x       = (const float*)d_in[0];
    const float* W_in    = (const float*)d_in[1];
    const float* ln_g    = (const float*)d_in[2];
    const float* ln_b    = (const float*)d_in[3];
    const float* W_gate  = (const float*)d_in[4];
    const float* b_gate  = (const float*)d_in[5];
    const float* eig_raw = (const float*)d_in[6];
    const float* W_out   = (const float*)d_in[7];
    float* out = (float*)d_out;

    char* ws = (char*)d_ws;
    unsigned short* xb   = (unsigned short*)(ws);                   // 32MB; reused as xln after gemm1
    unsigned short* xln  = (unsigned short*)(ws);
    unsigned short* hall = (unsigned short*)(ws + 33554432);        // 32MB
    unsigned short* Wib  = (unsigned short*)(ws + 67108864);        // 2MB
    unsigned short* Wob  = (unsigned short*)(ws + 69206016);        // 2MB
    unsigned short* WgT  = (unsigned short*)(ws + 71303168);        // 64KB
    float* beta_buf = (float*)(ws + 71368704);                      // 1MB
    float* cum_buf  = (float*)(ws + 72417280);                      // 1MB
    float* c15c     = (float*)(ws + 73465856);                      // 64KB
    float* hc15     = (float*)(ws + 73531392);                      // 4MB
    float* carry_in = (float*)(ws + 77725696);                      // 4MB  (end ~78.2MB)

    float* xp = out;                       // d_out head doubles as xp scratch
    float* h_final = out + 16777216;

    convert_all_kernel<<<18464, 256, 0, stream>>>(x, W_in, W_out, W_gate, xb, Wib, Wob, WgT);

    dim3 gg(128, 8);
    gemm_bt_kernel<<<gg, 256, 0, stream>>>(xb, Wib, xp, MROWS, HID, HID);

    mid_kernel<<<1024, 256, 0, stream>>>(xp, ln_g, ln_b, WgT, b_gate, eig_raw,
                                         xln, beta_buf, cum_buf, c15c, hc15);

    scan2_kernel<<<16, 256, 0, stream>>>(c15c, hc15, carry_in, h_final);
    scan3_kernel<<<1024, 256, 0, stream>>>(cum_buf, beta_buf, xln, carry_in, hall);

    gemm_bt_kernel<<<gg, 256, 0, stream>>>(hall, Wob, out, MROWS, HID, HID);
}

// Round 4
// 272.823 us; speedup vs baseline: 1.9697x; 1.1536x over previous
//
#include <hip/hip_runtime.h>
#include <hip/hip_bf16.h>
#include <stdint.h>

// Problem constants
#define BATCH 4
#define SEQ   4096
#define HID   1024
#define NH    16
#define HD    64
#define CS    16
#define NCH   256          // SEQ/CS
#define MROWS 16384        // BATCH*SEQ

typedef __attribute__((ext_vector_type(8))) __bf16 bf16x8;
typedef __attribute__((ext_vector_type(4))) float  f32x4;

__device__ __forceinline__ unsigned short f2bf(float f) {
    union { float f; unsigned u; } x; x.f = f;
    unsigned r = x.u + 0x7FFFu + ((x.u >> 16) & 1u);   // RNE
    return (unsigned short)(r >> 16);
}
__device__ __forceinline__ float bf2f(unsigned short v) {
    union { unsigned u; float f; } x; x.u = ((unsigned)v) << 16;
    return x.f;
}

__device__ __forceinline__ void async_copy16(void* lds, const void* g) {
    __builtin_amdgcn_global_load_lds(
        (const __attribute__((address_space(1))) unsigned int*)g,
        (__attribute__((address_space(3))) unsigned int*)lds,
        16, 0, 0);
}

// ---------------------------------------------------------------- convert (all inputs, one kernel)
__global__ __launch_bounds__(256) void convert_all_kernel(
    const float* __restrict__ x, const float* __restrict__ W_in,
    const float* __restrict__ W_out, const float* __restrict__ W_gate,
    unsigned short* __restrict__ xb, unsigned short* __restrict__ Wib,
    unsigned short* __restrict__ Wob, unsigned short* __restrict__ Wgb)
{
    int i = blockIdx.x * 256 + threadIdx.x;
    const float4* src; ushort4* dst; int j;
    if (i < 4194304)      { src = (const float4*)x;      dst = (ushort4*)xb;  j = i; }
    else if (i < 4456448) { src = (const float4*)W_in;   dst = (ushort4*)Wib; j = i - 4194304; }
    else if (i < 4718592) { src = (const float4*)W_out;  dst = (ushort4*)Wob; j = i - 4456448; }
    else if (i < 4726784) { src = (const float4*)W_gate; dst = (ushort4*)Wgb; j = i - 4718592; }
    else return;
    float4 v = src[j];
    ushort4 o;
    o.x = f2bf(v.x); o.y = f2bf(v.y); o.z = f2bf(v.z); o.w = f2bf(v.w);
    dst[j] = o;
}

// ---------------------------------------------------------------- GEMM (C = A @ B^T), bf16 in, fp32 out
// 128x128 tile, BK=64, 4 waves (2x2 of 64x64), XOR-swizzled LDS
__global__ __launch_bounds__(256, 2) void gemm_bt_kernel(
    const unsigned short* __restrict__ A,
    const unsigned short* __restrict__ Bm,
    float* __restrict__ C, int M, int N, int K)
{
    __shared__ unsigned short As[128 * 64];
    __shared__ unsigned short Bs[128 * 64];
    const int t = threadIdx.x;
    const int lane = t & 63, w = t >> 6;
    const int wm = w >> 1, wn = w & 1;
    const size_t bm = (size_t)blockIdx.x * 128;
    const size_t bn = (size_t)blockIdx.y * 128;

    f32x4 acc[4][4];
#pragma unroll
    for (int x = 0; x < 4; x++)
#pragma unroll
        for (int y = 0; y < 4; y++)
            acc[x][y] = (f32x4){0.f, 0.f, 0.f, 0.f};

    const int srow = lane >> 3;
    const int gc   = (lane & 7) ^ (srow & 7);      // swizzled global chunk
    const int scol = gc * 8;
    const unsigned short* Ag = A + (bm + w * 32 + srow) * (size_t)K + scol;
    const unsigned short* Bg = Bm + (bn + w * 32 + srow) * (size_t)K + scol;
    unsigned short* Al = As + (w * 32 + srow) * 64 + (lane & 7) * 8;
    unsigned short* Bl = Bs + (w * 32 + srow) * 64 + (lane & 7) * 8;

    const int fr = lane & 15, fq = lane >> 4;
    const int rl = fr & 7;

    for (int k0 = 0; k0 < K; k0 += 64) {
#pragma unroll
        for (int r = 0; r < 4; r++) {
            async_copy16(Al + r * 8 * 64, Ag + (size_t)r * 8 * K + k0);
            async_copy16(Bl + r * 8 * 64, Bg + (size_t)r * 8 * K + k0);
        }
        __syncthreads();
#pragma unroll
        for (int kk = 0; kk < 64; kk += 32) {
            const int c = (kk >> 3) + fq;
            const int pc = c ^ rl;
            bf16x8 af[4], bfv[4];
#pragma unroll
            for (int x = 0; x < 4; x++) {
                af[x]  = *(const bf16x8*)(As + (wm * 64 + x * 16 + fr) * 64 + pc * 8);
                bfv[x] = *(const bf16x8*)(Bs + (wn * 64 + x * 16 + fr) * 64 + pc * 8);
            }
#pragma unroll
            for (int x = 0; x < 4; x++)
#pragma unroll
                for (int y = 0; y < 4; y++)
                    acc[x][y] = __builtin_amdgcn_mfma_f32_16x16x32_bf16(af[x], bfv[y], acc[x][y], 0, 0, 0);
        }
        __syncthreads();
    }

#pragma unroll
    for (int x = 0; x < 4; x++) {
#pragma unroll
        for (int y = 0; y < 4; y++) {
            size_t r0 = bm + wm * 64 + x * 16 + fq * 4;
            size_t c  = bn + wn * 64 + y * 16 + fr;
#pragma unroll
            for (int rg = 0; rg < 4; rg++)
                C[(r0 + rg) * (size_t)N + c] = acc[x][y][rg];
        }
    }
}

// ---------------------------------------------------------------- mid: LN + MFMA gates + scan1
// One block per 16-row chunk. LDS ~45KB -> 3 blocks/CU.
__global__ __launch_bounds__(256) void mid_kernel(
    const float* __restrict__ xp,
    const float* __restrict__ ln_g, const float* __restrict__ ln_b,
    const unsigned short* __restrict__ Wgb,   // bf16 [32][1024]
    const float* __restrict__ bg, const float* __restrict__ eig_raw,
    unsigned short* __restrict__ xln,         // out: [MROWS][1024] bf16
    float* __restrict__ beta_buf,             // out: [MROWS][16]
    float* __restrict__ cum_out,              // out: [1024][16][16]
    float* __restrict__ c15c,                 // out: [1024][16]
    float* __restrict__ hc15)                 // out: [1024][1024]
{
    __shared__ unsigned short sx[16][1032];   // 33KB, +8 pad
    __shared__ float red[4][2][64][4];        // 8KB partial gate accs
    __shared__ float sg[16][32];
    __shared__ float scum[16][16];
    __shared__ float sm15[16][16];
    const int t = threadIdx.x, lane = t & 63, w = t >> 6;
    const int bn = blockIdx.x;
    const size_t m0 = (size_t)(bn >> 8) * SEQ + (size_t)(bn & 255) * 16;

    // ---- LayerNorm (row r = t>>4, 64 elems per thread)
    const int r = t >> 4, u = t & 15;
    {
        const float* row = xp + (m0 + r) * 1024;
        float4 v[16];
        float s = 0.f, s2 = 0.f;
#pragma unroll
        for (int i = 0; i < 16; i++) {
            v[i] = *(const float4*)(row + u * 4 + i * 64);
            s  += v[i].x + v[i].y + v[i].z + v[i].w;
            s2 += v[i].x * v[i].x + v[i].y * v[i].y + v[i].z * v[i].z + v[i].w * v[i].w;
        }
#pragma unroll
        for (int off = 1; off < 16; off <<= 1) {
            s  += __shfl_xor(s, off, 64);
            s2 += __shfl_xor(s2, off, 64);
        }
        const float mu = s * (1.f / 1024.f);
        const float var = s2 * (1.f / 1024.f) - mu * mu;
        const float sc = rsqrtf(var + 1e-5f);
        unsigned short* orow = xln + (m0 + r) * 1024;
#pragma unroll
        for (int i = 0; i < 16; i++) {
            const int k = u * 4 + i * 64;
            float4 g4 = *(const float4*)(ln_g + k);
            float4 b4 = *(const float4*)(ln_b + k);
            ushort4 o;
            o.x = f2bf((v[i].x - mu) * sc * g4.x + b4.x);
            o.y = f2bf((v[i].y - mu) * sc * g4.y + b4.y);
            o.z = f2bf((v[i].z - mu) * sc * g4.z + b4.z);
            o.w = f2bf((v[i].w - mu) * sc * g4.w + b4.w);
            *(ushort4*)&sx[r][k] = o;
            *(ushort4*)(orow + k) = o;
        }
    }
    __syncthreads();

    // ---- gates via MFMA: wave w covers K in [w*256,(w+1)*256)
    const int fr = lane & 15, fq = lane >> 4;
    {
        f32x4 acc0 = (f32x4){0.f,0.f,0.f,0.f}, acc1 = (f32x4){0.f,0.f,0.f,0.f};
        const unsigned short* Wr0 = Wgb + (size_t)fr * 1024;
        const unsigned short* Wr1 = Wgb + (size_t)(16 + fr) * 1024;
#pragma unroll
        for (int ks = 0; ks < 8; ks++) {
            const int k0 = w * 256 + ks * 32 + fq * 8;
            bf16x8 af = *(const bf16x8*)&sx[fr][k0];
            bf16x8 b0 = *(const bf16x8*)(Wr0 + k0);
            bf16x8 b1 = *(const bf16x8*)(Wr1 + k0);
            acc0 = __builtin_amdgcn_mfma_f32_16x16x32_bf16(af, b0, acc0, 0, 0, 0);
            acc1 = __builtin_amdgcn_mfma_f32_16x16x32_bf16(af, b1, acc1, 0, 0, 0);
        }
        *(f32x4*)&red[w][0][lane][0] = acc0;
        *(f32x4*)&red[w][1][lane][0] = acc1;
    }
    __syncthreads();
    if (t < 128) {
        const int y = t >> 6, l = t & 63;
        f32x4 s = *(const f32x4*)&red[0][y][l][0];
#pragma unroll
        for (int ww = 1; ww < 4; ww++) {
            f32x4 p = *(const f32x4*)&red[ww][y][l][0];
            s[0] += p[0]; s[1] += p[1]; s[2] += p[2]; s[3] += p[3];
        }
        const int col = y * 16 + (l & 15);
        const int row0 = (l >> 4) * 4;
        const float bias = bg[col];
#pragma unroll
        for (int rg = 0; rg < 4; rg++)
            sg[row0 + rg][col] = 1.f / (1.f + expf(-(s[rg] + bias)));
    }
    __syncthreads();

    // ---- cumprod of a = tanh(eig)*alpha
    if (t < 16) {
        const float ev = tanhf(eig_raw[t]);
        float c = 1.f;
#pragma unroll
        for (int i = 0; i < 16; i++) { c *= ev * sg[i][t]; scum[i][t] = c; }
    }
    // beta out
    beta_buf[(m0 + r) * 16 + u] = sg[r][16 + u];
    __syncthreads();

    // ---- M15 (beta folded), cum/c15 out
    {
        const int j = t >> 4, h = t & 15;
        const float cum15 = scum[15][h];
        const float cpad = (j == 0) ? 1.f : scum[j - 1][h];
        float mv;
        if (j == 15) mv = 1.f;
        else mv = (fabsf(cpad) > 1e-8f) ? (cum15 / cpad) : 0.f;
        sm15[j][h] = mv * sg[j][16 + h];
        cum_out[(size_t)bn * 256 + t] = scum[j][h];
        if (t < 16) c15c[bn * 16 + t] = scum[15][t];
    }
    __syncthreads();

    // ---- hc15
    {
        const int h = t >> 4, d0 = (t & 15) * 4;
        float a0 = 0.f, a1 = 0.f, a2 = 0.f, a3 = 0.f;
#pragma unroll
        for (int j = 0; j < 16; j++) {
            const float m = sm15[j][h];
            ushort4 bv = *(const ushort4*)&sx[j][h * 64 + d0];
            a0 += m * bf2f(bv.x); a1 += m * bf2f(bv.y);
            a2 += m * bf2f(bv.z); a3 += m * bf2f(bv.w);
        }
        float4 o = { a0, a1, a2, a3 };
        *(float4*)(hc15 + (size_t)bn * 1024 + h * 64 + d0) = o;
    }
}

// ---------------------------------------------------------------- scan phase 2 (sequential carry)
__global__ __launch_bounds__(64) void scan2_kernel(
    const float* __restrict__ c15c,      // [1024][16]
    const float* __restrict__ hc15,      // [1024][1024]
    float* __restrict__ carry_in,        // [1024][1024]
    float* __restrict__ h_final)         // [4][1024]
{
    const int p = blockIdx.x * 64 + threadIdx.x;   // 0..4095
    const int b = p >> 10, hd = p & 1023, h = hd >> 6;
    float carry = 0.f;
#pragma unroll 8
    for (int n = 0; n < NCH; n++) {
        const size_t bn = (size_t)b * NCH + n;
        const float c15 = c15c[bn * 16 + h];
        carry_in[bn * 1024 + hd] = carry;
        carry = c15 * carry + hc15[bn * 1024 + hd];
    }
    h_final[(size_t)b * 1024 + hd] = carry;
}

// ---------------------------------------------------------------- scan phase 3 (reconstruct h_all, bf16)
__global__ __launch_bounds__(256) void scan3_kernel(
    const float* __restrict__ cum_buf,
    const float* __restrict__ beta_buf,
    const unsigned short* __restrict__ xln,
    const float* __restrict__ carry_in,
    unsigned short* __restrict__ hall)          // [MROWS][1024] bf16
{
    __shared__ float scum[16][16];
    __shared__ float sbeta[16][16];
    __shared__ float sm[16][16][16];            // [i][j][h], includes beta
    __shared__ unsigned short sx[16][1024];
    const int t = threadIdx.x;
    const int bn = blockIdx.x;
    const size_t m0 = (size_t)(bn >> 8) * SEQ + (size_t)(bn & 255) * 16;

    scum[t >> 4][t & 15]  = cum_buf[(size_t)bn * 256 + t];
    sbeta[t >> 4][t & 15] = beta_buf[(m0 + (t >> 4)) * 16 + (t & 15)];
#pragma unroll
    for (int i = 0; i < 16; i++)
        *(ushort4*)&sx[i][t * 4] = *(const ushort4*)(xln + (m0 + i) * 1024 + t * 4);
    __syncthreads();

    {
        const int i = t >> 4, h = t & 15;
        const float ci = scum[i][h];
#pragma unroll
        for (int j = 0; j < 16; j++) {
            float mv;
            if (j > i) mv = 0.f;
            else if (j == i) mv = 1.f;
            else {
                const float cpad = (j == 0) ? 1.f : scum[j - 1][h];
                mv = (fabsf(cpad) > 1e-8f) ? (ci / cpad) : 0.f;
            }
            sm[i][j][h] = mv * sbeta[j][h];
        }
    }
    __syncthreads();

    {
        const int h = t >> 4, d0 = (t & 15) * 4;
        float4 car = *(const float4*)(carry_in + (size_t)bn * 1024 + h * 64 + d0);
#pragma unroll
        for (int i = 0; i < 16; i++) {
            float a0 = 0.f, a1 = 0.f, a2 = 0.f, a3 = 0.f;
            for (int j = 0; j <= i; j++) {
                const float m = sm[i][j][h];
                ushort4 bv = *(const ushort4*)&sx[j][h * 64 + d0];
                a0 += m * bf2f(bv.x); a1 += m * bf2f(bv.y);
                a2 += m * bf2f(bv.z); a3 += m * bf2f(bv.w);
            }
            const float ci = scum[i][h];
            ushort4 o;
            o.x = f2bf(ci * car.x + a0);
            o.y = f2bf(ci * car.y + a1);
            o.z = f2bf(ci * car.z + a2);
            o.w = f2bf(ci * car.w + a3);
            *(ushort4*)(hall + (m0 + i) * 1024 + h * 64 + d0) = o;
        }
    }
}

// ---------------------------------------------------------------- launch
extern "C" void kernel_launch(void* const* d_in, const int* in_sizes, int n_in,
                              void* d_out, int out_size, void* d_ws, size_t ws_size,
                              hipStream_t stream)
{
    const float* x       = (const float*)d_in[0];
    const float* W_in    = (const float*)d_in[1];
    const float* ln_g    = (const float*)d_in[2];
    const float* ln_b    = (const float*)d_in[3];
    const float* W_gate  = (const float*)d_in[4];
    const float* b_gate  = (const float*)d_in[5];
    const float* eig_raw = (const float*)d_in[6];
    const float* W_out   = (const float*)d_in[7];
    float* out = (float*)d_out;

    char* ws = (char*)d_ws;
    unsigned short* xb   = (unsigned short*)(ws);                   // 32MB; reused as xln after gemm1
    unsigned short* xln  = (unsigned short*)(ws);
    unsigned short* hall = (unsigned short*)(ws + 33554432);        // 32MB
    unsigned short* Wib  = (unsigned short*)(ws + 67108864);        // 2MB
    unsigned short* Wob  = (unsigned short*)(ws + 69206016);        // 2MB
    unsigned short* Wgb  = (unsigned short*)(ws + 71303168);        // 64KB
    float* beta_buf = (float*)(ws + 71368704);                      // 1MB
    float* cum_buf  = (float*)(ws + 72417280);                      // 1MB
    float* c15c     = (float*)(ws + 73465856);                      // 64KB
    float* hc15     = (float*)(ws + 73531392);                      // 4MB
    float* carry_in = (float*)(ws + 77725696);                      // 4MB  (end ~78.2MB)

    float* xp = out;                       // d_out head doubles as xp scratch
    float* h_final = out + 16777216;

    convert_all_kernel<<<18464, 256, 0, stream>>>(x, W_in, W_out, W_gate, xb, Wib, Wob, Wgb);

    dim3 gg(128, 8);
    gemm_bt_kernel<<<gg, 256, 0, stream>>>(xb, Wib, xp, MROWS, HID, HID);

    mid_kernel<<<1024, 256, 0, stream>>>(xp, ln_g, ln_b, Wgb, b_gate, eig_raw,
                                         xln, beta_buf, cum_buf, c15c, hc15);

    scan2_kernel<<<64, 64, 0, stream>>>(c15c, hc15, carry_in, h_final);
    scan3_kernel<<<1024, 256, 0, stream>>>(cum_buf, beta_buf, xln, carry_in, hall);

    gemm_bt_kernel<<<gg, 256, 0, stream>>>(hall, Wob, out, MROWS, HID, HID);
}

// Round 5
// 268.525 us; speedup vs baseline: 2.0013x; 1.0160x over previous
//
#include <hip/hip_runtime.h>
#include <hip/hip_bf16.h>
#include <stdint.h>

// Problem constants
#define BATCH 4
#define SEQ   4096
#define HID   1024
#define NH    16
#define HD    64
#define CS    16
#define NCH   256          // SEQ/CS
#define MROWS 16384        // BATCH*SEQ

typedef __attribute__((ext_vector_type(8))) __bf16 bf16x8;
typedef __attribute__((ext_vector_type(4))) float  f32x4;

__device__ __forceinline__ unsigned short f2bf(float f) {
    union { float f; unsigned u; } x; x.f = f;
    unsigned r = x.u + 0x7FFFu + ((x.u >> 16) & 1u);   // RNE
    return (unsigned short)(r >> 16);
}
__device__ __forceinline__ float bf2f(unsigned short v) {
    union { unsigned u; float f; } x; x.u = ((unsigned)v) << 16;
    return x.f;
}

__device__ __forceinline__ void async_copy16(void* lds, const void* g) {
    __builtin_amdgcn_global_load_lds(
        (const __attribute__((address_space(1))) unsigned int*)g,
        (__attribute__((address_space(3))) unsigned int*)lds,
        16, 0, 0);
}

// ---------------------------------------------------------------- convert (all inputs, one kernel)
__global__ __launch_bounds__(256) void convert_all_kernel(
    const float* __restrict__ x, const float* __restrict__ W_in,
    const float* __restrict__ W_out, const float* __restrict__ W_gate,
    unsigned short* __restrict__ xb, unsigned short* __restrict__ Wib,
    unsigned short* __restrict__ Wob, unsigned short* __restrict__ Wgb)
{
    int i = blockIdx.x * 256 + threadIdx.x;
    const float4* src; ushort4* dst; int j;
    if (i < 4194304)      { src = (const float4*)x;      dst = (ushort4*)xb;  j = i; }
    else if (i < 4456448) { src = (const float4*)W_in;   dst = (ushort4*)Wib; j = i - 4194304; }
    else if (i < 4718592) { src = (const float4*)W_out;  dst = (ushort4*)Wob; j = i - 4456448; }
    else if (i < 4726784) { src = (const float4*)W_gate; dst = (ushort4*)Wgb; j = i - 4718592; }
    else return;
    float4 v = src[j];
    ushort4 o;
    o.x = f2bf(v.x); o.y = f2bf(v.y); o.z = f2bf(v.z); o.w = f2bf(v.w);
    dst[j] = o;
}

// ---------------------------------------------------------------- GEMM (C = A @ B^T), bf16 in, fp32 out
// 128x128 tile, BK=64, 4 waves (2x2 of 64x64), XOR-swizzled LDS
__global__ __launch_bounds__(256, 2) void gemm_bt_kernel(
    const unsigned short* __restrict__ A,
    const unsigned short* __restrict__ Bm,
    float* __restrict__ C, int M, int N, int K)
{
    __shared__ unsigned short As[128 * 64];
    __shared__ unsigned short Bs[128 * 64];
    const int t = threadIdx.x;
    const int lane = t & 63, w = t >> 6;
    const int wm = w >> 1, wn = w & 1;
    const size_t bm = (size_t)blockIdx.x * 128;
    const size_t bn = (size_t)blockIdx.y * 128;

    f32x4 acc[4][4];
#pragma unroll
    for (int x = 0; x < 4; x++)
#pragma unroll
        for (int y = 0; y < 4; y++)
            acc[x][y] = (f32x4){0.f, 0.f, 0.f, 0.f};

    const int srow = lane >> 3;
    const int gc   = (lane & 7) ^ (srow & 7);      // swizzled global chunk
    const int scol = gc * 8;
    const unsigned short* Ag = A + (bm + w * 32 + srow) * (size_t)K + scol;
    const unsigned short* Bg = Bm + (bn + w * 32 + srow) * (size_t)K + scol;
    unsigned short* Al = As + (w * 32 + srow) * 64 + (lane & 7) * 8;
    unsigned short* Bl = Bs + (w * 32 + srow) * 64 + (lane & 7) * 8;

    const int fr = lane & 15, fq = lane >> 4;
    const int rl = fr & 7;

    for (int k0 = 0; k0 < K; k0 += 64) {
#pragma unroll
        for (int r = 0; r < 4; r++) {
            async_copy16(Al + r * 8 * 64, Ag + (size_t)r * 8 * K + k0);
            async_copy16(Bl + r * 8 * 64, Bg + (size_t)r * 8 * K + k0);
        }
        __syncthreads();
#pragma unroll
        for (int kk = 0; kk < 64; kk += 32) {
            const int c = (kk >> 3) + fq;
            const int pc = c ^ rl;
            bf16x8 af[4], bfv[4];
#pragma unroll
            for (int x = 0; x < 4; x++) {
                af[x]  = *(const bf16x8*)(As + (wm * 64 + x * 16 + fr) * 64 + pc * 8);
                bfv[x] = *(const bf16x8*)(Bs + (wn * 64 + x * 16 + fr) * 64 + pc * 8);
            }
#pragma unroll
            for (int x = 0; x < 4; x++)
#pragma unroll
                for (int y = 0; y < 4; y++)
                    acc[x][y] = __builtin_amdgcn_mfma_f32_16x16x32_bf16(af[x], bfv[y], acc[x][y], 0, 0, 0);
        }
        __syncthreads();
    }

#pragma unroll
    for (int x = 0; x < 4; x++) {
#pragma unroll
        for (int y = 0; y < 4; y++) {
            size_t r0 = bm + wm * 64 + x * 16 + fq * 4;
            size_t c  = bn + wn * 64 + y * 16 + fr;
#pragma unroll
            for (int rg = 0; rg < 4; rg++)
                C[(r0 + rg) * (size_t)N + c] = acc[x][y][rg];
        }
    }
}

// ---------------------------------------------------------------- mid: LN + MFMA gates + scan1 (prefix form)
__global__ __launch_bounds__(256) void mid_kernel(
    const float* __restrict__ xp,
    const float* __restrict__ ln_g, const float* __restrict__ ln_b,
    const unsigned short* __restrict__ Wgb,   // bf16 [32][1024]
    const float* __restrict__ bg, const float* __restrict__ eig_raw,
    unsigned short* __restrict__ xln,         // out: [MROWS][1024] bf16
    float* __restrict__ beta_buf,             // out: [MROWS][16]
    float* __restrict__ cum_out,              // out: [1024][16][16]
    float* __restrict__ c15c,                 // out: [1024][16]
    float* __restrict__ hc15)                 // out: [1024][1024]
{
    __shared__ unsigned short sx[16][1032];   // 33KB, +8 pad
    __shared__ float red[4][2][64][4];        // 8KB partial gate accs
    __shared__ float sg[16][32];
    __shared__ float scum[16][16];
    const int t = threadIdx.x, lane = t & 63, w = t >> 6;
    const int bn = blockIdx.x;
    const size_t m0 = (size_t)(bn >> 8) * SEQ + (size_t)(bn & 255) * 16;

    // ---- LayerNorm (row r = t>>4, 64 elems per thread)
    const int r = t >> 4, u = t & 15;
    {
        const float* row = xp + (m0 + r) * 1024;
        float4 v[16];
        float s = 0.f, s2 = 0.f;
#pragma unroll
        for (int i = 0; i < 16; i++) {
            v[i] = *(const float4*)(row + u * 4 + i * 64);
            s  += v[i].x + v[i].y + v[i].z + v[i].w;
            s2 += v[i].x * v[i].x + v[i].y * v[i].y + v[i].z * v[i].z + v[i].w * v[i].w;
        }
#pragma unroll
        for (int off = 1; off < 16; off <<= 1) {
            s  += __shfl_xor(s, off, 64);
            s2 += __shfl_xor(s2, off, 64);
        }
        const float mu = s * (1.f / 1024.f);
        const float var = s2 * (1.f / 1024.f) - mu * mu;
        const float sc = rsqrtf(var + 1e-5f);
        unsigned short* orow = xln + (m0 + r) * 1024;
#pragma unroll
        for (int i = 0; i < 16; i++) {
            const int k = u * 4 + i * 64;
            float4 g4 = *(const float4*)(ln_g + k);
            float4 b4 = *(const float4*)(ln_b + k);
            ushort4 o;
            o.x = f2bf((v[i].x - mu) * sc * g4.x + b4.x);
            o.y = f2bf((v[i].y - mu) * sc * g4.y + b4.y);
            o.z = f2bf((v[i].z - mu) * sc * g4.z + b4.z);
            o.w = f2bf((v[i].w - mu) * sc * g4.w + b4.w);
            *(ushort4*)&sx[r][k] = o;
            *(ushort4*)(orow + k) = o;
        }
    }
    __syncthreads();

    // ---- gates via MFMA: wave w covers K in [w*256,(w+1)*256)
    const int fr = lane & 15, fq = lane >> 4;
    {
        f32x4 acc0 = (f32x4){0.f,0.f,0.f,0.f}, acc1 = (f32x4){0.f,0.f,0.f,0.f};
        const unsigned short* Wr0 = Wgb + (size_t)fr * 1024;
        const unsigned short* Wr1 = Wgb + (size_t)(16 + fr) * 1024;
#pragma unroll
        for (int ks = 0; ks < 8; ks++) {
            const int k0 = w * 256 + ks * 32 + fq * 8;
            bf16x8 af = *(const bf16x8*)&sx[fr][k0];
            bf16x8 b0 = *(const bf16x8*)(Wr0 + k0);
            bf16x8 b1 = *(const bf16x8*)(Wr1 + k0);
            acc0 = __builtin_amdgcn_mfma_f32_16x16x32_bf16(af, b0, acc0, 0, 0, 0);
            acc1 = __builtin_amdgcn_mfma_f32_16x16x32_bf16(af, b1, acc1, 0, 0, 0);
        }
        *(f32x4*)&red[w][0][lane][0] = acc0;
        *(f32x4*)&red[w][1][lane][0] = acc1;
    }
    __syncthreads();
    if (t < 128) {
        const int y = t >> 6, l = t & 63;
        f32x4 s = *(const f32x4*)&red[0][y][l][0];
#pragma unroll
        for (int ww = 1; ww < 4; ww++) {
            f32x4 p = *(const f32x4*)&red[ww][y][l][0];
            s[0] += p[0]; s[1] += p[1]; s[2] += p[2]; s[3] += p[3];
        }
        const int col = y * 16 + (l & 15);
        const int row0 = (l >> 4) * 4;
        const float bias = bg[col];
#pragma unroll
        for (int rg = 0; rg < 4; rg++)
            sg[row0 + rg][col] = 1.f / (1.f + expf(-(s[rg] + bias)));
    }
    __syncthreads();

    // ---- cumprod of a = tanh(eig)*alpha
    if (t < 16) {
        const float ev = tanhf(eig_raw[t]);
        float c = 1.f;
#pragma unroll
        for (int i = 0; i < 16; i++) { c *= ev * sg[i][t]; scum[i][t] = c; }
    }
    // beta out
    beta_buf[(m0 + r) * 16 + u] = sg[r][16 + u];
    __syncthreads();

    // cum/c15 out
    cum_out[(size_t)bn * 256 + t] = scum[t >> 4][t & 15];
    if (t < 16) c15c[bn * 16 + t] = scum[15][t];

    // ---- hc15 via prefix form: hc15 = cum15 * sum_{j<15} bb[j]/cpad[j] + bb[15]
    {
        const int h = t >> 4, d0 = (t & 15) * 4;
        float s0 = 0.f, s1 = 0.f, s2 = 0.f, s3 = 0.f;
        float b0 = 0.f, b1 = 0.f, b2 = 0.f, b3 = 0.f;
        float cprev = 1.f;
#pragma unroll
        for (int j = 0; j < 16; j++) {
            const float bt = sg[j][16 + h];
            ushort4 xv = *(const ushort4*)&sx[j][h * 64 + d0];
            b0 = bt * bf2f(xv.x); b1 = bt * bf2f(xv.y);
            b2 = bt * bf2f(xv.z); b3 = bt * bf2f(xv.w);
            if (j < 15) {
                const float inv = (fabsf(cprev) > 1e-8f) ? (1.f / cprev) : 0.f;
                s0 += b0 * inv; s1 += b1 * inv; s2 += b2 * inv; s3 += b3 * inv;
                cprev = scum[j][h];
            }
        }
        const float c15 = scum[15][h];
        float4 o = { c15 * s0 + b0, c15 * s1 + b1, c15 * s2 + b2, c15 * s3 + b3 };
        *(float4*)(hc15 + (size_t)bn * 1024 + h * 64 + d0) = o;
    }
}

// ---------------------------------------------------------------- scan phase 2 (sequential carry)
__global__ __launch_bounds__(64) void scan2_kernel(
    const float* __restrict__ c15c,      // [1024][16]
    const float* __restrict__ hc15,      // [1024][1024]
    float* __restrict__ carry_in,        // [1024][1024]
    float* __restrict__ h_final)         // [4][1024]
{
    const int p = blockIdx.x * 64 + threadIdx.x;   // 0..4095
    const int b = p >> 10, hd = p & 1023, h = hd >> 6;
    float carry = 0.f;
#pragma unroll 8
    for (int n = 0; n < NCH; n++) {
        const size_t bn = (size_t)b * NCH + n;
        const float c15 = c15c[bn * 16 + h];
        carry_in[bn * 1024 + hd] = carry;
        carry = c15 * carry + hc15[bn * 1024 + hd];
    }
    h_final[(size_t)b * 1024 + hd] = carry;
}

// ---------------------------------------------------------------- scan phase 3: prefix form, register-resident
// h[i] = cum[i]*(carry + sum_{j<i} bb[j]/cpad[j]) + bb[i]
__global__ __launch_bounds__(256) void scan3_kernel(
    const float* __restrict__ cum_buf,
    const float* __restrict__ beta_buf,
    const unsigned short* __restrict__ xln,
    const float* __restrict__ carry_in,
    unsigned short* __restrict__ hall)          // [MROWS][1024] bf16
{
    __shared__ float scum[16][16];
    __shared__ float sbeta[16][16];
    const int t = threadIdx.x;
    const int bn = blockIdx.x;
    const size_t m0 = (size_t)(bn >> 8) * SEQ + (size_t)(bn & 255) * 16;

    scum[t >> 4][t & 15]  = cum_buf[(size_t)bn * 256 + t];
    sbeta[t >> 4][t & 15] = beta_buf[(m0 + (t >> 4)) * 16 + (t & 15)];
    __syncthreads();

    const int h = t >> 4, dq = t & 15;
    const size_t off = h * 64 + dq * 4;
    float4 s = *(const float4*)(carry_in + (size_t)bn * 1024 + off);
    float cprev = 1.f;
#pragma unroll
    for (int i = 0; i < 16; i++) {
        ushort4 xv = *(const ushort4*)(xln + (m0 + i) * 1024 + off);
        const float bt = sbeta[i][h];
        const float b0 = bt * bf2f(xv.x), b1 = bt * bf2f(xv.y),
                    b2 = bt * bf2f(xv.z), b3 = bt * bf2f(xv.w);
        const float ci = scum[i][h];
        ushort4 o;
        o.x = f2bf(ci * s.x + b0); o.y = f2bf(ci * s.y + b1);
        o.z = f2bf(ci * s.z + b2); o.w = f2bf(ci * s.w + b3);
        *(ushort4*)(hall + (m0 + i) * 1024 + off) = o;
        const float inv = (fabsf(cprev) > 1e-8f) ? (1.f / cprev) : 0.f;
        s.x += b0 * inv; s.y += b1 * inv; s.z += b2 * inv; s.w += b3 * inv;
        cprev = ci;
    }
}

// ---------------------------------------------------------------- launch
extern "C" void kernel_launch(void* const* d_in, const int* in_sizes, int n_in,
                              void* d_out, int out_size, void* d_ws, size_t ws_size,
                              hipStream_t stream)
{
    const float* x       = (const float*)d_in[0];
    const float* W_in    = (const float*)d_in[1];
    const float* ln_g    = (const float*)d_in[2];
    const float* ln_b    = (const float*)d_in[3];
    const float* W_gate  = (const float*)d_in[4];
    const float* b_gate  = (const float*)d_in[5];
    const float* eig_raw = (const float*)d_in[6];
    const float* W_out   = (const float*)d_in[7];
    float* out = (float*)d_out;

    char* ws = (char*)d_ws;
    unsigned short* xb   = (unsigned short*)(ws);                   // 32MB; reused as xln after gemm1
    unsigned short* xln  = (unsigned short*)(ws);
    unsigned short* hall = (unsigned short*)(ws + 33554432);        // 32MB
    unsigned short* Wib  = (unsigned short*)(ws + 67108864);        // 2MB
    unsigned short* Wob  = (unsigned short*)(ws + 69206016);        // 2MB
    unsigned short* Wgb  = (unsigned short*)(ws + 71303168);        // 64KB
    float* beta_buf = (float*)(ws + 71368704);                      // 1MB
    float* cum_buf  = (float*)(ws + 72417280);                      // 1MB
    float* c15c     = (float*)(ws + 73465856);                      // 64KB
    float* hc15     = (float*)(ws + 73531392);                      // 4MB
    float* carry_in = (float*)(ws + 77725696);                      // 4MB  (end ~78.2MB)

    float* xp = out;                       // d_out head doubles as xp scratch
    float* h_final = out + 16777216;

    convert_all_kernel<<<18464, 256, 0, stream>>>(x, W_in, W_out, W_gate, xb, Wib, Wob, Wgb);

    dim3 gg(128, 8);
    gemm_bt_kernel<<<gg, 256, 0, stream>>>(xb, Wib, xp, MROWS, HID, HID);

    mid_kernel<<<1024, 256, 0, stream>>>(xp, ln_g, ln_b, Wgb, b_gate, eig_raw,
                                         xln, beta_buf, cum_buf, c15c, hc15);

    scan2_kernel<<<64, 64, 0, stream>>>(c15c, hc15, carry_in, h_final);
    scan3_kernel<<<1024, 256, 0, stream>>>(cum_buf, beta_buf, xln, carry_in, hall);

    gemm_bt_kernel<<<gg, 256, 0, stream>>>(hall, Wob, out, MROWS, HID, HID);
}